// Round 8
// baseline (366.053 us; speedup 1.0000x reference)
//
#include <hip/hip_runtime.h>
#include <hip/hip_bf16.h>

// MEASUREMENT ROUND: REPEAT-stretched kernels for per-dispatch attribution.
// Repeats are result-scaled (1/REPEAT) so outputs are unchanged (f32 noise
// ~1e-3 << threshold 2283). Kernels are cache-invariant (R2/R5 replay
// evidence), so shown_dur / REPEAT = true duration.

typedef __bf16 bf16x8 __attribute__((ext_vector_type(8)));
typedef float f32x16 __attribute__((ext_vector_type(16)));

// ---- Gram of [nrows x 64] (optional gather) via bf16 MFMA, LDS-free --------
template<bool GATHER, int REPEAT>
__global__ __launch_bounds__(256) void gram_kernel(
    const float* __restrict__ emb, const int* __restrict__ idx,
    int nrows, int nwaves_total, float* __restrict__ partial) {
    const int t = threadIdx.x, lane = t & 63, wave = t >> 6;
    const int c = lane & 31, kh = lane >> 5;
    const int wid = blockIdx.x * 4 + wave;
    const int step = nwaves_total * 16;

    f32x16 g00 = {}, g01 = {}, g11 = {};
    for (int rep = 0; rep < REPEAT; ++rep) {
        float cur0[8], cur1[8];
        int k0 = wid * 16;
        if (k0 < nrows) {
            const int kb = k0 + kh * 8;
#pragma unroll
            for (int j = 0; j < 8; ++j) {
                const size_t rb = (GATHER ? (size_t)idx[kb + j] : (size_t)(kb + j)) * 64;
                cur0[j] = emb[rb + c];
                cur1[j] = emb[rb + 32 + c];
            }
        }
        for (; k0 < nrows; k0 += step) {
            float nx0[8], nx1[8];
            const int k1 = k0 + step;
            if (k1 < nrows) {                   // prefetch next chunk
                const int kb = k1 + kh * 8;
#pragma unroll
                for (int j = 0; j < 8; ++j) {
                    const size_t rb = (GATHER ? (size_t)idx[kb + j] : (size_t)(kb + j)) * 64;
                    nx0[j] = emb[rb + c];
                    nx1[j] = emb[rb + 32 + c];
                }
            } else {
#pragma unroll
                for (int j = 0; j < 8; ++j) { nx0[j] = 0.f; nx1[j] = 0.f; }
            }
            bf16x8 f0, f1;                      // nrows % 16 == 0 here
#pragma unroll
            for (int j = 0; j < 8; ++j) {
                f0[j] = (__bf16)cur0[j];
                f1[j] = (__bf16)cur1[j];
            }
            g00 = __builtin_amdgcn_mfma_f32_32x32x16_bf16(f0, f0, g00, 0, 0, 0);
            g01 = __builtin_amdgcn_mfma_f32_32x32x16_bf16(f0, f1, g01, 0, 0, 0);
            g11 = __builtin_amdgcn_mfma_f32_32x32x16_bf16(f1, f1, g11, 0, 0, 0);
#pragma unroll
            for (int j = 0; j < 8; ++j) { cur0[j] = nx0[j]; cur1[j] = nx1[j]; }
        }
    }

    __shared__ float red[3072];
    __syncthreads();
    for (int w = 0; w < 4; ++w) {
        if (wave == w) {
#pragma unroll
            for (int r = 0; r < 16; ++r) {
                const int cell = ((r & 3) + 8 * (r >> 2) + 4 * kh) * 32 + c;
                if (w == 0) {
                    red[cell] = g00[r]; red[1024 + cell] = g01[r]; red[2048 + cell] = g11[r];
                } else {
                    red[cell] += g00[r]; red[1024 + cell] += g01[r]; red[2048 + cell] += g11[r];
                }
            }
        }
        __syncthreads();
    }
    const float invR = 1.0f / (float)REPEAT;
    float* outp = partial + (size_t)blockIdx.x * 3072;
    for (int i = t; i < 3072; i += 256) outp[i] = red[i] * invR;
}

// ---- pos: one wave per batch element (R6 variant), REPEAT-stretched --------
template<int REPEAT>
__global__ __launch_bounds__(256) void pos_kernel(
    const int* __restrict__ users, const int* __restrict__ hist,
    const float* __restrict__ user_emb, const float* __restrict__ item_emb,
    const float* __restrict__ Hw, int batch, int histL,
    float* __restrict__ p1, float* __restrict__ p2) {
    const int t = threadIdx.x, lane = t & 63, wave = t >> 6;
    const int w = blockIdx.x * 4 + wave;        // wave id == batch index
    if (w >= batch) return;
    const int iu = users[w];
    const int k = lane & 15, g = lane >> 4;
    const float4 vu = *reinterpret_cast<const float4*>(user_emb + (size_t)iu * 64 + k * 4);
    const float4 vh = *reinterpret_cast<const float4*>(Hw + k * 4);
    const float4 uh = make_float4(vu.x * vh.x, vu.y * vh.y, vu.z * vh.z, vu.w * vh.w);
    const int* hrow = hist + (size_t)iu * histL;

    float s1 = 0.f, s2 = 0.f;
    for (int rep = 0; rep < REPEAT; ++rep) {
        int l = g;
        for (; l + 12 < histL; l += 16) {       // 4 groups x ILP-4
            int it[4];
#pragma unroll
            for (int u = 0; u < 4; ++u) it[u] = hrow[l + 4 * u];
            float d[4];
#pragma unroll
            for (int u = 0; u < 4; ++u) {
                const float4 v = *reinterpret_cast<const float4*>(
                    item_emb + (size_t)it[u] * 64 + k * 4);
                d[u] = v.x * uh.x + v.y * uh.y + v.z * uh.z + v.w * uh.w;
            }
#pragma unroll
            for (int u = 0; u < 4; ++u) {
                float dd = d[u];
                dd += __shfl_xor(dd, 1, 16);
                dd += __shfl_xor(dd, 2, 16);
                dd += __shfl_xor(dd, 4, 16);
                dd += __shfl_xor(dd, 8, 16);
                s1 += dd;                        // replicated x16; scaled at end
                s2 = fmaf(dd, dd, s2);
            }
        }
        for (; l < histL; l += 4) {
            const int it = hrow[l];
            const float4 v = *reinterpret_cast<const float4*>(
                item_emb + (size_t)it * 64 + k * 4);
            float dd = v.x * uh.x + v.y * uh.y + v.z * uh.z + v.w * uh.w;
            dd += __shfl_xor(dd, 1, 16);
            dd += __shfl_xor(dd, 2, 16);
            dd += __shfl_xor(dd, 4, 16);
            dd += __shfl_xor(dd, 8, 16);
            s1 += dd;
            s2 = fmaf(dd, dd, s2);
        }
    }
    s1 += __shfl_xor(s1, 16, 64); s1 += __shfl_xor(s1, 32, 64);
    s2 += __shfl_xor(s2, 16, 64); s2 += __shfl_xor(s2, 32, 64);
    const float invR = 0.0625f / (float)REPEAT;
    if (lane == 0) { p1[w] = s1 * invR; p2[w] = s2 * invR; }
}

// ---- sumsq of flat f32 buffer (unchanged) ----------------------------------
__global__ __launch_bounds__(256) void sumsq_kernel(
    const float* __restrict__ x, int n4, float* __restrict__ part) {
    float s = 0.f;
    for (int i = blockIdx.x * 256 + threadIdx.x; i < n4; i += gridDim.x * 256) {
        const float4 v = reinterpret_cast<const float4*>(x)[i];
        s = fmaf(v.x, v.x, s); s = fmaf(v.y, v.y, s);
        s = fmaf(v.z, v.z, s); s = fmaf(v.w, v.w, s);
    }
#pragma unroll
    for (int off = 32; off >= 1; off >>= 1) s += __shfl_xor(s, off, 64);
    __shared__ float r[4];
    if ((threadIdx.x & 63) == 0) r[threadIdx.x >> 6] = s;
    __syncthreads();
    if (threadIdx.x == 0) part[blockIdx.x] = r[0] + r[1] + r[2] + r[3];
}

__global__ __launch_bounds__(256) void reduce_gram_kernel(
    const float* __restrict__ pa, int na, float* __restrict__ GI,
    const float* __restrict__ pb, int nb, float* __restrict__ GU) {
    const int e = blockIdx.x * 256 + threadIdx.x;   // grid 24 -> 6144
    const float* p; float* dst; int n, ee;
    if (e < 3072)      { p = pa; dst = GI; n = na; ee = e; }
    else if (e < 6144) { p = pb; dst = GU; n = nb; ee = e - 3072; }
    else return;
    float s[8] = {0.f,0.f,0.f,0.f,0.f,0.f,0.f,0.f};
    int b = 0;
    for (; b + 8 <= n; b += 8)
#pragma unroll
        for (int u = 0; u < 8; ++u) s[u] += p[(size_t)(b + u) * 3072 + ee];
    for (; b < n; ++b) s[0] += p[(size_t)b * 3072 + ee];
    dst[ee] = ((s[0]+s[1])+(s[2]+s[3])) + ((s[4]+s[5])+(s[6]+s[7]));
}

__global__ __launch_bounds__(256) void finalize_kernel(
    const float* __restrict__ GI, const float* __restrict__ GU,
    const float* __restrict__ Hw,
    const float* __restrict__ p1, const float* __restrict__ p2, int npos,
    const float* __restrict__ ssq, int nss, float* __restrict__ outp) {
    const int t = threadIdx.x;
    float tsum = 0.f, trace = 0.f, s1 = 0.f, s2 = 0.f, su = 0.f;
    for (int e = t; e < 3072; e += 256) {
        const int tile = e >> 10, r = (e & 1023) >> 5, cc = e & 31;
        const int i = (tile == 2) ? r + 32 : r;
        const int j = (tile == 0) ? cc : cc + 32;
        const float w = (tile == 1) ? 2.0f : 1.0f;
        const float gi = GI[e];
        tsum += w * gi * GU[e] * Hw[i] * Hw[j];
        if (i == j) trace += gi;
    }
    for (int e = t; e < npos; e += 256) { s1 += p1[e]; s2 += p2[e]; }
    for (int e = t; e < nss; e += 256) su += ssq[e];
#pragma unroll
    for (int off = 32; off >= 1; off >>= 1) {
        tsum += __shfl_xor(tsum, off, 64);
        trace += __shfl_xor(trace, off, 64);
        s1 += __shfl_xor(s1, off, 64);
        s2 += __shfl_xor(s2, off, 64);
        su += __shfl_xor(su, off, 64);
    }
    __shared__ float rr[4][5];
    if ((t & 63) == 0) {
        rr[t >> 6][0] = tsum; rr[t >> 6][1] = trace; rr[t >> 6][2] = s1;
        rr[t >> 6][3] = s2;   rr[t >> 6][4] = su;
    }
    __syncthreads();
    if (t == 0) {
        const float tt = rr[0][0] + rr[1][0] + rr[2][0] + rr[3][0];
        const float tr = rr[0][1] + rr[1][1] + rr[2][1] + rr[3][1];
        const float a1 = rr[0][2] + rr[1][2] + rr[2][2] + rr[3][2];
        const float a2 = rr[0][3] + rr[1][3] + rr[2][3] + rr[3][3];
        const float au = rr[0][4] + rr[1][4] + rr[2][4] + rr[3][4];
        const float reg = 1e-4f * (sqrtf(au) + sqrtf(tr));
        const float loss = 0.5f * tt + 0.5f * a2 - 2.0f * a1 + reg;
        outp[0] = loss; outp[1] = reg; outp[2] = reg;
    }
}

extern "C" void kernel_launch(void* const* d_in, const int* in_sizes, int n_in,
                              void* d_out, int out_size, void* d_ws, size_t ws_size,
                              hipStream_t stream) {
    const int*   users    = (const int*)d_in[0];
    const int*   hist     = (const int*)d_in[1];
    const float* user_emb = (const float*)d_in[2];
    const float* item_emb = (const float*)d_in[3];
    const float* Hw       = (const float*)d_in[4];
    float* outp = (float*)d_out;
    float* ws   = (float*)d_ws;

    const int n_users = in_sizes[2] / 64;            // 200000
    const int n_items = in_sizes[3] / 64;            // 1000000
    const int batch   = in_sizes[0];                 // 4096
    const int histL   = in_sizes[1] / n_users;       // 200

    int NB_ITEM = 1024;
    const int NB_USER = 64;
    const int NSS = 2048;

    // ws layout (floats)
    const size_t o_gi = 0, o_gu = 3072, o_p1 = 6144;
    const size_t o_p2 = o_p1 + (size_t)batch;
    const size_t o_ss = o_p2 + (size_t)batch;
    const size_t o_part = o_ss + NSS;
    long availf = (long)(ws_size / 4) - (long)o_part - (long)NB_USER * 3072;
    if ((long)NB_ITEM * 3072 > availf) {
        NB_ITEM = (int)(availf / 3072);
        if (NB_ITEM < 8) NB_ITEM = 8;
    }
    float* partA = ws + o_part;
    float* partB = partA + (size_t)NB_ITEM * 3072;

    gram_kernel<false, 3><<<NB_ITEM, 256, 0, stream>>>(     // item gram x3
        item_emb, nullptr, n_items, NB_ITEM * 4, partA);
    pos_kernel<5><<<(batch + 3) / 4, 256, 0, stream>>>(     // pos x5
        users, hist, user_emb, item_emb, Hw, batch, histL,
        ws + o_p1, ws + o_p2);
    gram_kernel<true, 1><<<NB_USER, 256, 0, stream>>>(
        user_emb, users, batch, NB_USER * 4, partB);
    sumsq_kernel<<<NSS, 256, 0, stream>>>(user_emb, in_sizes[2] / 4, ws + o_ss);
    reduce_gram_kernel<<<24, 256, 0, stream>>>(partA, NB_ITEM, ws + o_gi,
                                               partB, NB_USER, ws + o_gu);
    finalize_kernel<<<1, 256, 0, stream>>>(ws + o_gi, ws + o_gu, Hw,
                                           ws + o_p1, ws + o_p2, batch,
                                           ws + o_ss, NSS, outp);
}

// Round 9
// 111.680 us; speedup vs baseline: 3.2777x; 3.2777x over previous
//
#include <hip/hip_runtime.h>
#include <hip/hip_bf16.h>

typedef __bf16 bf16x8 __attribute__((ext_vector_type(8)));
typedef float f32x16 __attribute__((ext_vector_type(16)));

// ---- Gram body: G = E^T E over [nrows x 64] (optional gather), bf16 MFMA ----
// Per-wave 16-row chunks, scalar column loads feeding 32x32x16 fragments
// directly, one-chunk register prefetch. Proven 54 us/pass on item table.
template<bool GATHER>
static __device__ __forceinline__ void gram_body(
    const float* __restrict__ emb, const int* __restrict__ idx,
    int nrows, int nwaves_total, int blk,
    float* __restrict__ partial, float* __restrict__ red, int t) {
    const int lane = t & 63, wave = t >> 6;
    const int c = lane & 31, kh = lane >> 5;
    const int wid = blk * 4 + wave;
    const int step = nwaves_total * 16;

    f32x16 g00 = {}, g01 = {}, g11 = {};
    float cur0[8], cur1[8];

    int k0 = wid * 16;
    if (k0 < nrows) {
        const int kb = k0 + kh * 8;
#pragma unroll
        for (int j = 0; j < 8; ++j) {
            const size_t rb = (GATHER ? (size_t)idx[kb + j] : (size_t)(kb + j)) * 64;
            cur0[j] = emb[rb + c];
            cur1[j] = emb[rb + 32 + c];
        }
    }
    for (; k0 < nrows; k0 += step) {
        float nx0[8], nx1[8];
        const int k1 = k0 + step;
        if (k1 < nrows) {                       // prefetch next chunk
            const int kb = k1 + kh * 8;
#pragma unroll
            for (int j = 0; j < 8; ++j) {
                const size_t rb = (GATHER ? (size_t)idx[kb + j] : (size_t)(kb + j)) * 64;
                nx0[j] = emb[rb + c];
                nx1[j] = emb[rb + 32 + c];
            }
        } else {
#pragma unroll
            for (int j = 0; j < 8; ++j) { nx0[j] = 0.f; nx1[j] = 0.f; }
        }
        bf16x8 f0, f1;                          // nrows % 16 == 0 here
#pragma unroll
        for (int j = 0; j < 8; ++j) {
            f0[j] = (__bf16)cur0[j];
            f1[j] = (__bf16)cur1[j];
        }
        g00 = __builtin_amdgcn_mfma_f32_32x32x16_bf16(f0, f0, g00, 0, 0, 0);
        g01 = __builtin_amdgcn_mfma_f32_32x32x16_bf16(f0, f1, g01, 0, 0, 0);
        g11 = __builtin_amdgcn_mfma_f32_32x32x16_bf16(f1, f1, g11, 0, 0, 0);
#pragma unroll
        for (int j = 0; j < 8; ++j) { cur0[j] = nx0[j]; cur1[j] = nx1[j]; }
    }

    __syncthreads();
    for (int w = 0; w < 4; ++w) {
        if (wave == w) {
#pragma unroll
            for (int r = 0; r < 16; ++r) {
                const int cell = ((r & 3) + 8 * (r >> 2) + 4 * kh) * 32 + c;
                if (w == 0) {
                    red[cell] = g00[r]; red[1024 + cell] = g01[r]; red[2048 + cell] = g11[r];
                } else {
                    red[cell] += g00[r]; red[1024 + cell] += g01[r]; red[2048 + cell] += g11[r];
                }
            }
        }
        __syncthreads();
    }
    float* outp = partial + (size_t)blk * 3072;
    for (int i = t; i < 3072; i += 256) outp[i] = red[i];
}

__global__ __launch_bounds__(256) void gram_kernel(
    const float* __restrict__ emb, int nrows, int nwaves_total,
    float* __restrict__ partial) {
    __shared__ float red[3072];
    gram_body<false>(emb, nullptr, nrows, nwaves_total, blockIdx.x,
                     partial, red, threadIdx.x);
}

// ---- mix: pos (NP blocks) | sumsq (NSS) | user gram (NU) -------------------
__global__ __launch_bounds__(256) void mix_kernel(
    const int* __restrict__ users, const int* __restrict__ hist,
    const float* __restrict__ user_emb, const float* __restrict__ item_emb,
    const float* __restrict__ Hw, int batch, int histL, int n_users,
    int NP, int NSS, int NU,
    float* __restrict__ p1, float* __restrict__ p2,
    float* __restrict__ pss, float* __restrict__ partB) {
    __shared__ float red[3072];
    const int bid = blockIdx.x, t = threadIdx.x;

    if (bid < NP) {                              // ---- pos role (R6-proven)
        const int lane = t & 63, wave = t >> 6;
        const int w = bid * 4 + wave;            // wave id == batch index
        if (w >= batch) return;
        const int iu = users[w];
        const int k = lane & 15, g = lane >> 4;
        const float4 vu = *reinterpret_cast<const float4*>(user_emb + (size_t)iu * 64 + k * 4);
        const float4 vh = *reinterpret_cast<const float4*>(Hw + k * 4);
        const float4 uh = make_float4(vu.x * vh.x, vu.y * vh.y, vu.z * vh.z, vu.w * vh.w);
        const int* hrow = hist + (size_t)iu * histL;

        float s1 = 0.f, s2 = 0.f;
        int l = g;
        for (; l + 12 < histL; l += 16) {        // 4 groups x ILP-4
            int it[4];
#pragma unroll
            for (int u = 0; u < 4; ++u) it[u] = hrow[l + 4 * u];
            float d[4];
#pragma unroll
            for (int u = 0; u < 4; ++u) {
                const float4 v = *reinterpret_cast<const float4*>(
                    item_emb + (size_t)it[u] * 64 + k * 4);
                d[u] = v.x * uh.x + v.y * uh.y + v.z * uh.z + v.w * uh.w;
            }
#pragma unroll
            for (int u = 0; u < 4; ++u) {
                float dd = d[u];
                dd += __shfl_xor(dd, 1, 16);
                dd += __shfl_xor(dd, 2, 16);
                dd += __shfl_xor(dd, 4, 16);
                dd += __shfl_xor(dd, 8, 16);
                s1 += dd;                        // replicated x16; scaled below
                s2 = fmaf(dd, dd, s2);
            }
        }
        for (; l < histL; l += 4) {
            const int it = hrow[l];
            const float4 v = *reinterpret_cast<const float4*>(
                item_emb + (size_t)it * 64 + k * 4);
            float dd = v.x * uh.x + v.y * uh.y + v.z * uh.z + v.w * uh.w;
            dd += __shfl_xor(dd, 1, 16);
            dd += __shfl_xor(dd, 2, 16);
            dd += __shfl_xor(dd, 4, 16);
            dd += __shfl_xor(dd, 8, 16);
            s1 += dd;
            s2 = fmaf(dd, dd, s2);
        }
        s1 += __shfl_xor(s1, 16, 64); s1 += __shfl_xor(s1, 32, 64);
        s2 += __shfl_xor(s2, 16, 64); s2 += __shfl_xor(s2, 32, 64);
        if (lane == 0) { p1[w] = s1 * 0.0625f; p2[w] = s2 * 0.0625f; }
    } else if (bid < NP + NSS) {                 // ---- sumsq role
        const int cid = bid - NP;
        const int n4 = n_users * 16;
        float s = 0.f;
        for (int i = cid * 256 + t; i < n4; i += NSS * 256) {
            const float4 v = reinterpret_cast<const float4*>(user_emb)[i];
            s = fmaf(v.x, v.x, s); s = fmaf(v.y, v.y, s);
            s = fmaf(v.z, v.z, s); s = fmaf(v.w, v.w, s);
        }
#pragma unroll
        for (int off = 32; off >= 1; off >>= 1) s += __shfl_xor(s, off, 64);
        if ((t & 63) == 0) red[t >> 6] = s;
        __syncthreads();
        if (t == 0) pss[cid] = red[0] + red[1] + red[2] + red[3];
    } else {                                     // ---- user gram role
        gram_body<true>(user_emb, users, batch, NU * 4, bid - NP - NSS,
                        partB, red, t);
    }
}

// ---- stage-1 reduce of gram partials, 8-way partial-dim split --------------
// grid = 24 cell-blocks x 8 segs. part2[seg*6144 + e].
__global__ __launch_bounds__(256) void reduce_gram_kernel(
    const float* __restrict__ pa, int na,
    const float* __restrict__ pb, int nb, float* __restrict__ part2) {
    const int bid = blockIdx.x;
    const int cellblk = bid % 24, seg = bid / 24;
    const int e = cellblk * 256 + threadIdx.x;
    const float* p; int n, ee;
    if (e < 3072) { p = pa; n = na; ee = e; }
    else          { p = pb; n = nb; ee = e - 3072; }
    const int chunk = (n + 7) >> 3;
    const int b0 = seg * chunk;
    int b1 = b0 + chunk; if (b1 > n) b1 = n;
    float s[4] = {0.f, 0.f, 0.f, 0.f};
    int b = b0;
    for (; b + 4 <= b1; b += 4)
#pragma unroll
        for (int u = 0; u < 4; ++u) s[u] += p[(size_t)(b + u) * 3072 + ee];
    for (; b < b1; ++b) s[0] += p[(size_t)b * 3072 + ee];
    part2[(size_t)seg * 6144 + e] = (s[0] + s[1]) + (s[2] + s[3]);
}

// ---- finalize: 1024 threads, consumes part2 directly -----------------------
__global__ __launch_bounds__(1024) void finalize_kernel(
    const float* __restrict__ part2, const float* __restrict__ Hw,
    const float* __restrict__ p1, const float* __restrict__ p2, int npos,
    const float* __restrict__ pss, int nss, float* __restrict__ outp) {
    const int t = threadIdx.x;
    float tsum = 0.f, trace = 0.f, s1 = 0.f, s2 = 0.f, su = 0.f;
    for (int e = t; e < 3072; e += 1024) {
        float gi = 0.f, gu = 0.f;
#pragma unroll
        for (int seg = 0; seg < 8; ++seg) {
            gi += part2[(size_t)seg * 6144 + e];
            gu += part2[(size_t)seg * 6144 + 3072 + e];
        }
        const int tile = e >> 10, r = (e & 1023) >> 5, cc = e & 31;
        const int i = (tile == 2) ? r + 32 : r;
        const int j = (tile == 0) ? cc : cc + 32;
        const float w = (tile == 1) ? 2.0f : 1.0f;
        tsum += w * gi * gu * Hw[i] * Hw[j];
        if (i == j) trace += gi;
    }
    for (int e = t; e < npos; e += 1024) { s1 += p1[e]; s2 += p2[e]; }
    for (int e = t; e < nss; e += 1024) su += pss[e];
#pragma unroll
    for (int off = 32; off >= 1; off >>= 1) {
        tsum += __shfl_xor(tsum, off, 64);
        trace += __shfl_xor(trace, off, 64);
        s1 += __shfl_xor(s1, off, 64);
        s2 += __shfl_xor(s2, off, 64);
        su += __shfl_xor(su, off, 64);
    }
    __shared__ float rr[16][5];
    if ((t & 63) == 0) {
        const int w = t >> 6;
        rr[w][0] = tsum; rr[w][1] = trace; rr[w][2] = s1;
        rr[w][3] = s2;   rr[w][4] = su;
    }
    __syncthreads();
    if (t == 0) {
        float a[5] = {0.f, 0.f, 0.f, 0.f, 0.f};
        for (int w = 0; w < 16; ++w)
#pragma unroll
            for (int q = 0; q < 5; ++q) a[q] += rr[w][q];
        const float reg = 1e-4f * (sqrtf(a[4]) + sqrtf(a[1]));
        const float loss = 0.5f * a[0] + 0.5f * a[3] - 2.0f * a[2] + reg;
        outp[0] = loss; outp[1] = reg; outp[2] = reg;
    }
}

extern "C" void kernel_launch(void* const* d_in, const int* in_sizes, int n_in,
                              void* d_out, int out_size, void* d_ws, size_t ws_size,
                              hipStream_t stream) {
    const int*   users    = (const int*)d_in[0];
    const int*   hist     = (const int*)d_in[1];
    const float* user_emb = (const float*)d_in[2];
    const float* item_emb = (const float*)d_in[3];
    const float* Hw       = (const float*)d_in[4];
    float* outp = (float*)d_out;
    float* ws   = (float*)d_ws;

    const int n_users = in_sizes[2] / 64;            // 200000
    const int n_items = in_sizes[3] / 64;            // 1000000
    const int batch   = in_sizes[0];                 // 4096
    const int histL   = in_sizes[1] / n_users;       // 200

    int NB_ITEM = 1024;                              // item-gram blocks
    const int NP  = (batch + 3) / 4;                 // pos blocks (1024)
    const int NSS = 512;                             // sumsq blocks
    const int NU  = 64;                              // user-gram blocks

    // ws layout (floats)
    const size_t o_p1 = 0;
    const size_t o_p2 = o_p1 + (size_t)batch;
    const size_t o_ss = o_p2 + (size_t)batch;
    const size_t o_part2 = o_ss + NSS;
    const size_t o_part = o_part2 + 8 * 6144;
    long availf = (long)(ws_size / 4) - (long)o_part - (long)NU * 3072;
    if ((long)NB_ITEM * 3072 > availf) {
        NB_ITEM = (int)(availf / 3072);
        if (NB_ITEM < 8) NB_ITEM = 8;
    }
    float* partA = ws + o_part;
    float* partB = partA + (size_t)NB_ITEM * 3072;

    gram_kernel<<<NB_ITEM, 256, 0, stream>>>(
        item_emb, n_items, NB_ITEM * 4, partA);
    mix_kernel<<<NP + NSS + NU, 256, 0, stream>>>(
        users, hist, user_emb, item_emb, Hw, batch, histL, n_users,
        NP, NSS, NU, ws + o_p1, ws + o_p2, ws + o_ss, partB);
    reduce_gram_kernel<<<24 * 8, 256, 0, stream>>>(
        partA, NB_ITEM, partB, NU, ws + o_part2);
    finalize_kernel<<<1, 1024, 0, stream>>>(
        ws + o_part2, Hw, ws + o_p1, ws + o_p2, batch,
        ws + o_ss, NSS, outp);
}